// Round 2
// baseline (469.711 us; speedup 1.0000x reference)
//
#include <hip/hip_runtime.h>
#include <hip/hip_bf16.h>

#define N_NODES 100000
#define D 64

// ---------- Pass B: histogram of dst ----------
__global__ void hist_kernel(const int* __restrict__ dst, int* __restrict__ counts,
                            int n_edges) {
    int e = blockIdx.x * blockDim.x + threadIdx.x;
    if (e >= n_edges) return;
    atomicAdd(&counts[dst[e]], 1);
}

// ---------- Pass C: exclusive scan (single block, 1024 threads) ----------
// Writes both offsets[] and cursor[] (cursor is consumed by fill_kernel's atomics).
__global__ void scan_kernel(const int* __restrict__ counts,
                            int* __restrict__ offsets,
                            int* __restrict__ cursor, int n) {
    __shared__ int ssum[1024];
    int tid = threadIdx.x;
    int per = (n + 1023) / 1024;
    int start = tid * per;
    int end = min(start + per, n);
    int sum = 0;
    for (int i = start; i < end; i++) sum += counts[i];
    ssum[tid] = sum;
    __syncthreads();
    // Hillis-Steele inclusive scan over 1024 partials
    for (int off = 1; off < 1024; off <<= 1) {
        int v = (tid >= off) ? ssum[tid - off] : 0;
        __syncthreads();
        ssum[tid] += v;
        __syncthreads();
    }
    int base = (tid == 0) ? 0 : ssum[tid - 1];
    for (int i = start; i < end; i++) {
        offsets[i] = base;
        cursor[i] = base;
        base += counts[i];
    }
}

// ---------- Pass D: bucket-fill sorted_src ----------
__global__ void fill_kernel(const int* __restrict__ src, const int* __restrict__ dst,
                            int* __restrict__ cursor, int* __restrict__ sorted_src,
                            int n_edges) {
    int e = blockIdx.x * blockDim.x + threadIdx.x;
    if (e >= n_edges) return;
    int d = dst[e];
    int pos = atomicAdd(&cursor[d], 1);
    sorted_src[pos] = src[e];
}

// ---------- Pass E: gather — one wave per node, lane = feature column ----------
__global__ void gather_kernel(const float* __restrict__ feat,
                              const int* __restrict__ offsets,
                              const int* __restrict__ counts,
                              const int* __restrict__ sorted_src,
                              float* __restrict__ out) {
    int node = blockIdx.x * (blockDim.x >> 6) + (threadIdx.x >> 6);
    int lane = threadIdx.x & 63;
    if (node >= N_NODES) return;
    int off = offsets[node];
    int deg = counts[node];
    float acc = 0.0f;
    for (int k0 = 0; k0 < deg; k0 += 64) {
        int sv = (k0 + lane < deg) ? sorted_src[off + k0 + lane] : 0;
        int kmax = min(64, deg - k0);
        #pragma unroll 4
        for (int k = 0; k < kmax; k++) {
            int s = __shfl(sv, k);
            acc += feat[(long long)s * D + lane];
        }
    }
    out[(long long)node * D + lane] = (deg > 0) ? acc / (float)deg : 0.0f;
}

// ---------- Fallback path (atomic scatter) if ws too small ----------
__global__ void gcn_scatter(const float* __restrict__ feat,
                            const int* __restrict__ src,
                            const int* __restrict__ dst,
                            float* __restrict__ out,
                            float* __restrict__ deg, int n_edges) {
    long long gtid = (long long)blockIdx.x * blockDim.x + threadIdx.x;
    int edge = (int)(gtid >> 6);
    int lane = threadIdx.x & 63;
    if (edge >= n_edges) return;
    int s = src[edge];
    int d = dst[edge];
    atomicAdd(&out[(long long)d * D + lane], feat[(long long)s * D + lane]);
    if (lane == 0) atomicAdd(&deg[d], 1.0f);
}
__global__ void gcn_finalize(float* __restrict__ out, const float* __restrict__ deg,
                             int total) {
    int i = blockIdx.x * blockDim.x + threadIdx.x;
    if (i >= total) return;
    float dg = deg[i >> 6];
    out[i] = (dg > 0.0f) ? out[i] / dg : 0.0f;
}

extern "C" void kernel_launch(void* const* d_in, const int* in_sizes, int n_in,
                              void* d_out, int out_size, void* d_ws, size_t ws_size,
                              hipStream_t stream) {
    const float* feat = (const float*)d_in[0];
    const int* src = (const int*)d_in[1];
    const int* dst = (const int*)d_in[2];
    float* out = (float*)d_out;
    int n_edges = in_sizes[1];
    int total = N_NODES * D;
    int block = 256;

    size_t need = (size_t)(3 * N_NODES + n_edges) * sizeof(int);
    if (ws_size < need) {
        // Fallback: atomic scatter (round-1 behavior)
        float* deg = (float*)d_ws;
        hipMemsetAsync(out, 0, (size_t)total * sizeof(float), stream);
        hipMemsetAsync(deg, 0, (size_t)N_NODES * sizeof(float), stream);
        long long threads = (long long)n_edges * 64;
        int grid = (int)((threads + block - 1) / block);
        gcn_scatter<<<grid, block, 0, stream>>>(feat, src, dst, out, deg, n_edges);
        gcn_finalize<<<(total + block - 1) / block, block, 0, stream>>>(out, deg, total);
        return;
    }

    int* counts = (int*)d_ws;
    int* offsets = counts + N_NODES;
    int* cursor = offsets + N_NODES;
    int* sorted_src = cursor + N_NODES;

    hipMemsetAsync(counts, 0, (size_t)N_NODES * sizeof(int), stream);

    int egrid = (n_edges + block - 1) / block;
    hist_kernel<<<egrid, block, 0, stream>>>(dst, counts, n_edges);
    scan_kernel<<<1, 1024, 0, stream>>>(counts, offsets, cursor, N_NODES);
    fill_kernel<<<egrid, block, 0, stream>>>(src, dst, cursor, sorted_src, n_edges);

    int waves_per_block = block / 64;
    int ggrid = (N_NODES + waves_per_block - 1) / waves_per_block;
    gather_kernel<<<ggrid, block, 0, stream>>>(feat, offsets, counts, sorted_src, out);
}

// Round 3
// 253.560 us; speedup vs baseline: 1.8525x; 1.8525x over previous
//
#include <hip/hip_runtime.h>
#include <hip/hip_bf16.h>

#define N_NODES 100000
#define D 64
#define SCAN_BLK 1024

// ---------- histogram of dst ----------
__global__ void hist_kernel(const int* __restrict__ dst, int* __restrict__ counts,
                            int n_edges) {
    int e = blockIdx.x * blockDim.x + threadIdx.x;
    if (e < n_edges) atomicAdd(&counts[dst[e]], 1);
}

// ---------- scan level 1: per-1024-chunk sums ----------
__global__ void bsum_kernel(const int* __restrict__ counts, int* __restrict__ bsums,
                            int n) {
    __shared__ int s[SCAN_BLK];
    int i = blockIdx.x * SCAN_BLK + threadIdx.x;
    s[threadIdx.x] = (i < n) ? counts[i] : 0;
    __syncthreads();
    for (int off = SCAN_BLK / 2; off > 0; off >>= 1) {
        if (threadIdx.x < off) s[threadIdx.x] += s[threadIdx.x + off];
        __syncthreads();
    }
    if (threadIdx.x == 0) bsums[blockIdx.x] = s[0];
}

// ---------- scan level 2: exclusive scan of block sums (nb <= 1024) ----------
__global__ void bscan_kernel(int* __restrict__ bsums, int nb) {
    __shared__ int s[SCAN_BLK];
    int tid = threadIdx.x;
    s[tid] = (tid < nb) ? bsums[tid] : 0;
    __syncthreads();
    for (int off = 1; off < SCAN_BLK; off <<= 1) {
        int t = (tid >= off) ? s[tid - off] : 0;
        __syncthreads();
        s[tid] += t;
        __syncthreads();
    }
    if (tid < nb) bsums[tid] = (tid > 0) ? s[tid - 1] : 0;
}

// ---------- scan level 3: per-chunk exclusive scan + base ----------
__global__ void offs_kernel(const int* __restrict__ counts, const int* __restrict__ bsums,
                            int* __restrict__ offsets, int* __restrict__ cursor, int n) {
    __shared__ int s[SCAN_BLK];
    int tid = threadIdx.x;
    int i = blockIdx.x * SCAN_BLK + tid;
    int v = (i < n) ? counts[i] : 0;
    s[tid] = v;
    __syncthreads();
    for (int off = 1; off < SCAN_BLK; off <<= 1) {
        int t = (tid >= off) ? s[tid - off] : 0;
        __syncthreads();
        s[tid] += t;
        __syncthreads();
    }
    if (i < n) {
        int excl = s[tid] - v + bsums[blockIdx.x];
        offsets[i] = excl;
        cursor[i] = excl;
    }
}

// ---------- bucket-fill sorted_src ----------
__global__ void fill_kernel(const int* __restrict__ src, const int* __restrict__ dst,
                            int* __restrict__ cursor, int* __restrict__ sorted_src,
                            int n_edges) {
    int e = blockIdx.x * blockDim.x + threadIdx.x;
    if (e >= n_edges) return;
    int d = dst[e];
    int pos = atomicAdd(&cursor[d], 1);
    sorted_src[pos] = src[e];
}

// ---------- gather: one wave per node, lane = feature column ----------
__global__ void gather_kernel(const float* __restrict__ feat,
                              const int* __restrict__ offsets,
                              const int* __restrict__ counts,
                              const int* __restrict__ sorted_src,
                              float* __restrict__ out) {
    int node = blockIdx.x * (blockDim.x >> 6) + (threadIdx.x >> 6);
    int lane = threadIdx.x & 63;
    if (node >= N_NODES) return;
    int off = offsets[node];
    int deg = counts[node];
    float acc = 0.0f;
    for (int k0 = 0; k0 < deg; k0 += 64) {
        int sv = (k0 + lane < deg) ? sorted_src[off + k0 + lane] : 0;
        int kmax = min(64, deg - k0);
        #pragma unroll 4
        for (int k = 0; k < kmax; k++) {
            int s = __shfl(sv, k);
            acc += feat[(long long)s * D + lane];
        }
    }
    out[(long long)node * D + lane] = (deg > 0) ? acc / (float)deg : 0.0f;
}

extern "C" void kernel_launch(void* const* d_in, const int* in_sizes, int n_in,
                              void* d_out, int out_size, void* d_ws, size_t ws_size,
                              hipStream_t stream) {
    const float* feat = (const float*)d_in[0];
    const int* src = (const int*)d_in[1];
    const int* dst = (const int*)d_in[2];
    float* out = (float*)d_out;
    int n_edges = in_sizes[1];
    int block = 256;

    int* counts = (int*)d_ws;
    int* offsets = counts + N_NODES;
    int* cursor = offsets + N_NODES;
    int* sorted_src = cursor + N_NODES;
    int* bsums = sorted_src + n_edges;

    int nb = (N_NODES + SCAN_BLK - 1) / SCAN_BLK;  // 98

    hipMemsetAsync(counts, 0, (size_t)N_NODES * sizeof(int), stream);

    int egrid = (n_edges + block - 1) / block;
    hist_kernel<<<egrid, block, 0, stream>>>(dst, counts, n_edges);

    bsum_kernel<<<nb, SCAN_BLK, 0, stream>>>(counts, bsums, N_NODES);
    bscan_kernel<<<1, SCAN_BLK, 0, stream>>>(bsums, nb);
    offs_kernel<<<nb, SCAN_BLK, 0, stream>>>(counts, bsums, offsets, cursor, N_NODES);

    fill_kernel<<<egrid, block, 0, stream>>>(src, dst, cursor, sorted_src, n_edges);

    int waves_per_block = block / 64;
    int ggrid = (N_NODES + waves_per_block - 1) / waves_per_block;
    gather_kernel<<<ggrid, block, 0, stream>>>(feat, offsets, counts, sorted_src, out);
}

// Round 4
// 149.716 us; speedup vs baseline: 3.1373x; 1.6936x over previous
//
#include <hip/hip_runtime.h>
#include <hip/hip_bf16.h>

#define N_NODES 100000
#define D 64

// ---------- build: per-node linked list of incoming edges ----------
// next[e] is written at index e -> fully coalesced. head gets atomicExch.
__global__ void build_kernel(const int* __restrict__ dst,
                             int* __restrict__ head,
                             int* __restrict__ next, int n_edges) {
    int e = blockIdx.x * blockDim.x + threadIdx.x;
    if (e >= n_edges) return;
    int d = dst[e];
    int old = atomicExch(&head[d], e);
    next[e] = old;
}

// ---------- gather: 4 nodes per wave (4 independent chains), 16 lanes x float4 per row ----------
__global__ void gather_ll(const float* __restrict__ feat,
                          const int* __restrict__ src,
                          const int* __restrict__ head,
                          const int* __restrict__ next,
                          float* __restrict__ out) {
    int wave = (blockIdx.x * blockDim.x + threadIdx.x) >> 6;
    int lane = threadIdx.x & 63;
    int group = lane >> 4;   // 0..3 -> which node this 16-lane group handles
    int gl = lane & 15;      // column group: floats [gl*4, gl*4+4)

    int node = wave * 4 + group;
    bool valid = (node < N_NODES);
    int e = valid ? head[node] : -1;

    float4 acc = make_float4(0.f, 0.f, 0.f, 0.f);
    int deg = 0;
    while (__any(e >= 0)) {
        if (e >= 0) {
            int s = src[e];
            const float4 v = *reinterpret_cast<const float4*>(
                &feat[(size_t)s * D + gl * 4]);
            acc.x += v.x; acc.y += v.y; acc.z += v.z; acc.w += v.w;
            deg++;
            e = next[e];
        }
    }
    if (valid) {
        float inv = (deg > 0) ? 1.0f / (float)deg : 0.0f;
        float4 o = make_float4(acc.x * inv, acc.y * inv, acc.z * inv, acc.w * inv);
        *reinterpret_cast<float4*>(&out[(size_t)node * D + gl * 4]) = o;
    }
}

// ---------- fallback (atomic scatter) if ws too small ----------
__global__ void gcn_scatter(const float* __restrict__ feat,
                            const int* __restrict__ src,
                            const int* __restrict__ dst,
                            float* __restrict__ out,
                            float* __restrict__ deg, int n_edges) {
    long long gtid = (long long)blockIdx.x * blockDim.x + threadIdx.x;
    int edge = (int)(gtid >> 6);
    int lane = threadIdx.x & 63;
    if (edge >= n_edges) return;
    atomicAdd(&out[(long long)dst[edge] * D + lane],
              feat[(long long)src[edge] * D + lane]);
    if (lane == 0) atomicAdd(&deg[dst[edge]], 1.0f);
}
__global__ void gcn_finalize(float* __restrict__ out, const float* __restrict__ deg,
                             int total) {
    int i = blockIdx.x * blockDim.x + threadIdx.x;
    if (i >= total) return;
    float dg = deg[i >> 6];
    out[i] = (dg > 0.0f) ? out[i] / dg : 0.0f;
}

extern "C" void kernel_launch(void* const* d_in, const int* in_sizes, int n_in,
                              void* d_out, int out_size, void* d_ws, size_t ws_size,
                              hipStream_t stream) {
    const float* feat = (const float*)d_in[0];
    const int* src = (const int*)d_in[1];
    const int* dst = (const int*)d_in[2];
    float* out = (float*)d_out;
    int n_edges = in_sizes[1];
    int block = 256;

    size_t need = (size_t)(N_NODES + n_edges) * sizeof(int);
    if (ws_size < need) {
        float* deg = (float*)d_ws;
        int total = N_NODES * D;
        hipMemsetAsync(out, 0, (size_t)total * sizeof(float), stream);
        hipMemsetAsync(deg, 0, (size_t)N_NODES * sizeof(float), stream);
        long long threads = (long long)n_edges * 64;
        int grid = (int)((threads + block - 1) / block);
        gcn_scatter<<<grid, block, 0, stream>>>(feat, src, dst, out, deg, n_edges);
        gcn_finalize<<<(total + block - 1) / block, block, 0, stream>>>(out, deg, total);
        return;
    }

    int* head = (int*)d_ws;          // N_NODES
    int* next = head + N_NODES;      // n_edges

    // head = -1 everywhere (0xFF bytes == -1 as int)
    hipMemsetAsync(head, 0xFF, (size_t)N_NODES * sizeof(int), stream);

    int egrid = (n_edges + block - 1) / block;
    build_kernel<<<egrid, block, 0, stream>>>(dst, head, next, n_edges);

    // 4 nodes per wave, 4 waves per 256-block -> 16 nodes per block
    int nodes_per_block = (block / 64) * 4;
    int ggrid = (N_NODES + nodes_per_block - 1) / nodes_per_block;
    gather_ll<<<ggrid, block, 0, stream>>>(feat, src, head, next, out);
}

// Round 5
// 138.862 us; speedup vs baseline: 3.3826x; 1.0782x over previous
//
#include <hip/hip_runtime.h>
#include <hip/hip_bf16.h>

#define N_NODES 100000
#define D 64

// ---------- build: per-node linked list, head padded to spread atomic lines ----------
// slot[e] = (src[e], prev_head). next-write coalesced; atomicExch lines spread by PAD.
__global__ void build_kernel(const int* __restrict__ src,
                             const int* __restrict__ dst,
                             int* __restrict__ head, int pad,
                             int2* __restrict__ slot, int n_edges) {
    int e = blockIdx.x * blockDim.x + threadIdx.x;
    if (e >= n_edges) return;
    int d = dst[e];
    int old = atomicExch(&head[d * pad], e);
    slot[e] = make_int2(src[e], old);
}

// ---------- gather: 4 nodes per wave, 16 lanes x float4 per feature row ----------
__global__ void gather_ll(const float* __restrict__ feat,
                          const int* __restrict__ head, int pad,
                          const int2* __restrict__ slot,
                          float* __restrict__ out) {
    int wave = (blockIdx.x * blockDim.x + threadIdx.x) >> 6;
    int lane = threadIdx.x & 63;
    int group = lane >> 4;   // 0..3: node within wave
    int gl = lane & 15;      // column group: floats [gl*4, gl*4+4)

    int node = wave * 4 + group;
    bool valid = (node < N_NODES);
    int e = valid ? head[node * pad] : -1;

    float4 acc = make_float4(0.f, 0.f, 0.f, 0.f);
    int deg = 0;
    while (__any(e >= 0)) {
        if (e >= 0) {
            int2 sn = slot[e];               // one random 8B (one line) per step
            const float4 v = *reinterpret_cast<const float4*>(
                &feat[(size_t)sn.x * D + gl * 4]);
            acc.x += v.x; acc.y += v.y; acc.z += v.z; acc.w += v.w;
            deg++;
            e = sn.y;
        }
    }
    if (valid) {
        float inv = (deg > 0) ? 1.0f / (float)deg : 0.0f;
        float4 o = make_float4(acc.x * inv, acc.y * inv, acc.z * inv, acc.w * inv);
        *reinterpret_cast<float4*>(&out[(size_t)node * D + gl * 4]) = o;
    }
}

// ---------- fallback (atomic scatter) if ws too small ----------
__global__ void gcn_scatter(const float* __restrict__ feat,
                            const int* __restrict__ src,
                            const int* __restrict__ dst,
                            float* __restrict__ out,
                            float* __restrict__ deg, int n_edges) {
    long long gtid = (long long)blockIdx.x * blockDim.x + threadIdx.x;
    int edge = (int)(gtid >> 6);
    int lane = threadIdx.x & 63;
    if (edge >= n_edges) return;
    atomicAdd(&out[(long long)dst[edge] * D + lane],
              feat[(long long)src[edge] * D + lane]);
    if (lane == 0) atomicAdd(&deg[dst[edge]], 1.0f);
}
__global__ void gcn_finalize(float* __restrict__ out, const float* __restrict__ deg,
                             int total) {
    int i = blockIdx.x * blockDim.x + threadIdx.x;
    if (i >= total) return;
    float dg = deg[i >> 6];
    out[i] = (dg > 0.0f) ? out[i] / dg : 0.0f;
}

extern "C" void kernel_launch(void* const* d_in, const int* in_sizes, int n_in,
                              void* d_out, int out_size, void* d_ws, size_t ws_size,
                              hipStream_t stream) {
    const float* feat = (const float*)d_in[0];
    const int* src = (const int*)d_in[1];
    const int* dst = (const int*)d_in[2];
    float* out = (float*)d_out;
    int n_edges = in_sizes[1];
    int block = 256;

    // Pick the largest head padding that fits the workspace.
    size_t slot_bytes = (size_t)n_edges * sizeof(int2);
    int pad = 0;
    if (ws_size >= slot_bytes + (size_t)N_NODES * 16 * sizeof(int)) pad = 16;
    else if (ws_size >= slot_bytes + (size_t)N_NODES * 4 * sizeof(int)) pad = 4;
    else if (ws_size >= slot_bytes + (size_t)N_NODES * sizeof(int)) pad = 1;

    if (pad == 0) {
        // Fallback: atomic scatter
        float* deg = (float*)d_ws;
        int total = N_NODES * D;
        hipMemsetAsync(out, 0, (size_t)total * sizeof(float), stream);
        hipMemsetAsync(deg, 0, (size_t)N_NODES * sizeof(float), stream);
        long long threads = (long long)n_edges * 64;
        int grid = (int)((threads + block - 1) / block);
        gcn_scatter<<<grid, block, 0, stream>>>(feat, src, dst, out, deg, n_edges);
        gcn_finalize<<<(total + block - 1) / block, block, 0, stream>>>(out, deg, total);
        return;
    }

    int2* slot = (int2*)d_ws;                       // n_edges int2
    int* head = (int*)(slot + n_edges);             // N_NODES * pad ints

    hipMemsetAsync(head, 0xFF, (size_t)N_NODES * pad * sizeof(int), stream);

    int egrid = (n_edges + block - 1) / block;
    build_kernel<<<egrid, block, 0, stream>>>(src, dst, head, pad, slot, n_edges);

    int nodes_per_block = (block / 64) * 4;         // 16
    int ggrid = (N_NODES + nodes_per_block - 1) / nodes_per_block;
    gather_ll<<<ggrid, block, 0, stream>>>(feat, head, pad, slot, out);
}